// Round 14
// baseline (314.827 us; speedup 1.0000x reference)
//
#include <hip/hip_runtime.h>
#include <cstdint>
#include <cstddef>

// Problem constants (match reference)
#define NS 4000
#define NG 50000
#define NE 250000
#define DIM 128
#define NDST_TOT (NG + NS)          // 54000 combined CSR rows (sg then gs)

typedef __bf16 bf16_t;
typedef bf16_t bf16x8 __attribute__((ext_vector_type(8)));
typedef bf16_t bf16x4 __attribute__((ext_vector_type(4)));
typedef bf16_t bf16x2 __attribute__((ext_vector_type(2)));
typedef float floatx4 __attribute__((ext_vector_type(4)));

// packed edge meta: low 16 = src id (< 65536), high 16 = bf16 bits of ea
__device__ __forceinline__ unsigned pack_meta(int src, float ea) {
  union { bf16_t b; unsigned short u; } cv;
  cv.b = (bf16_t)ea;
  return (unsigned)src | ((unsigned)cv.u << 16);
}
// decode: src = mv & 0xFFFF; ea = __uint_as_float(mv & 0xFFFF0000u)

// ---------------------------------------------------------------------------
// Fused histogram + prep. Blocks [0, HIST_B): per-dst degree counts; the
// atomicAdd return IS the edge's rank within its dst (ushort) -> scatter
// needs no atomics. Blocks [HIST_B, ...): 8 weight transposes + bf16 x casts.
// ---------------------------------------------------------------------------
#define HIST_B 977                  // ceil(NE/256)
#define WT_TOT 143360               // 4*16384 + 2*32768 + 4096 + 8192
struct HPArgs {
  const int* sgd; const int* gsd;
  int* cnt; unsigned short* rank_sg; unsigned short* rank_gs;
  const float* W[8]; bf16_t* Wt[8]; int N[8]; int e0[8];
  const float* xm; bf16_t* xbm;
  const float* xg; bf16_t* xbg;
};

__global__ __launch_bounds__(256) void histprep(HPArgs a) {
  if (blockIdx.x < HIST_B) {
    int e = blockIdx.x * 256 + threadIdx.x;
    if (e < NE) {
      a.rank_sg[e] = (unsigned short)atomicAdd(a.cnt + a.sgd[e], 1);
      a.rank_gs[e] = (unsigned short)atomicAdd(a.cnt + NG + a.gsd[e], 1);
    }
  } else {
    int u = (blockIdx.x - HIST_B) * 256 + threadIdx.x;
    if (u < WT_TOT) {
      int c = 0;
#pragma unroll
      for (int i = 1; i < 8; i++) if (u >= a.e0[i]) c = i;
      int idx = u - a.e0[c];
      int N = a.N[c];
      int k = idx / N, n = idx - k * N;
      a.Wt[c][n * 128 + k] = (bf16_t)a.W[c][idx];
    } else if (u < WT_TOT + 128000) {
      int j = (u - WT_TOT) * 4;
      float4 v = *reinterpret_cast<const float4*>(a.xm + j);
      bf16x4 b;
      b[0] = (bf16_t)v.x; b[1] = (bf16_t)v.y; b[2] = (bf16_t)v.z; b[3] = (bf16_t)v.w;
      *reinterpret_cast<bf16x4*>(a.xbm + j) = b;
    } else {
      int j = (u - WT_TOT - 128000) * 4;
      float4 v = *reinterpret_cast<const float4*>(a.xg + j);
      bf16x4 b;
      b[0] = (bf16_t)v.x; b[1] = (bf16_t)v.y; b[2] = (bf16_t)v.z; b[3] = (bf16_t)v.w;
      *reinterpret_cast<bf16x4*>(a.xbg + j) = b;
    }
  }
}

// ---------------------------------------------------------------------------
// Single-kernel exclusive scan over n=54000 (53 blocks of 1024). Block b
// redundantly reduces cnt[0, b*1024) — block-parallel + coalesced (L2-hot,
// <=53k ints) — then scans its own chunk. NOTE: do NOT serialize onto one
// block (R8: 103 us from per-thread serial reads); redundant-parallel is fine.
// ---------------------------------------------------------------------------
__global__ __launch_bounds__(1024) void scan_f(const int* __restrict__ cnt,
                                               int* __restrict__ rp, int n) {
  __shared__ int wsum[16];
  __shared__ int base_s;
  int t = threadIdx.x;
  int lane = t & 63, w = t >> 6;
  // 1) prefix base = sum of all preceding chunks
  int lim = blockIdx.x * 1024;
  int s = 0;
  for (int i = t; i < lim; i += 1024) s += cnt[i];
#pragma unroll
  for (int off = 32; off > 0; off >>= 1) s += __shfl_down(s, off);
  if (lane == 0) wsum[w] = s;
  __syncthreads();
  if (t == 0) {
    int tot = 0;
#pragma unroll
    for (int i = 0; i < 16; i++) tot += wsum[i];
    base_s = tot;
  }
  __syncthreads();
  int base = base_s;
  // 2) exclusive scan of own chunk
  int i = blockIdx.x * 1024 + t;
  int v = (i < n) ? cnt[i] : 0;
  int x = v;
#pragma unroll
  for (int off = 1; off < 64; off <<= 1) {
    int y = __shfl_up(x, off);
    if (lane >= off) x += y;
  }
  if (lane == 63) wsum[w] = x;
  __syncthreads();
  if (w == 0 && lane < 16) {
    int ss = wsum[lane];
#pragma unroll
    for (int off = 1; off < 16; off <<= 1) {
      int y = __shfl_up(ss, off);
      if (lane >= off) ss += y;
    }
    wsum[lane] = ss;
  }
  __syncthreads();
  int incl = x + (w ? wsum[w - 1] : 0);
  if (i < n) rp[i] = base + incl - v;
  if (i == 0) rp[n] = 2 * NE;                // static total sentinel
}

// ---------------------------------------------------------------------------
// Fused scatter + layer-1 GEMMs, block-parity INTERLEAVED so scatter
// (memory-latency-bound) and GEMM (MFMA-bound) waves are co-resident from
// the start (R13's range split ran them mostly sequentially). Each scatter
// thread handles its sg AND gs edge (2 independent chains -> 2x store MLP).
// ---------------------------------------------------------------------------
struct SGArgs {
  // scatter
  const int* sgd; const int* gsd; const int* sgs; const int* gss;
  const float* easg; const float* eags;
  const int* rp; const unsigned short* rank_sg; const unsigned short* rank_gs;
  unsigned* meta;
  // gemm (5 configs)
  const bf16_t* X[5];
  const bf16_t* Wt[5];
  const float* Bv[5];
  bf16_t* Y[5];
  int M[5];
  int Ncol[5];
  int blk0[5];
};

__global__ __launch_bounds__(256) void scatgemm(SGArgs a) {
  int bi = blockIdx.x;
  int gemm_b;
  if (bi < 2 * HIST_B) {
    if ((bi & 1) == 0) {
      // ---- scatter role: one sg edge + one gs edge per thread ----
      int t = (bi >> 1) * 256 + threadIdx.x;
      if (t < NE) {
        int d1 = a.sgd[t];
        int d2 = a.gsd[t];
        unsigned p1 = pack_meta(a.sgs[t], a.easg[t]);
        unsigned p2 = pack_meta(a.gss[t], a.eags[t]);
        int o1 = a.rp[d1] + a.rank_sg[t];
        int o2 = a.rp[NG + d2] + a.rank_gs[t];
        a.meta[o1] = p1;
        a.meta[o2] = p2;
      }
      return;
    }
    gemm_b = bi >> 1;                        // 0..976
  } else {
    gemm_b = HIST_B + (bi - 2 * HIST_B);     // 977..
  }
  int c = 0;
#pragma unroll
  for (int i = 1; i < 5; i++) if (gemm_b >= a.blk0[i]) c = i;
  const bf16_t* X = a.X[c];
  const bf16_t* Wt = a.Wt[c];
  const float* B = a.Bv[c];
  bf16_t* Y = a.Y[c];
  int M = a.M[c];
  int N = a.Ncol[c];

  int wv = threadIdx.x >> 6, lane = threadIdx.x & 63;
  int m16 = lane & 15, quad = lane >> 4;
  int row0 = (gemm_b - a.blk0[c]) * 64 + wv * 16;
  int arow = row0 + m16;
  const bf16_t* xp = X + (size_t)arow * DIM + quad * 8;

  bf16x8 afrag[4];
#pragma unroll
  for (int kk = 0; kk < 4; kk++) {
    bf16x8 av = {};
    if (arow < M) av = *reinterpret_cast<const bf16x8*>(xp + kk * 32);
    afrag[kk] = av;
  }

  int ncols = N >> 4;
  for (int nt = 0; nt < ncols; nt++) {
    int col = nt * 16 + m16;
    const bf16_t* bptr = Wt + (size_t)col * DIM + quad * 8;
    floatx4 acc = {0.f, 0.f, 0.f, 0.f};
#pragma unroll
    for (int kk = 0; kk < 4; kk++) {
      bf16x8 b = *reinterpret_cast<const bf16x8*>(bptr + kk * 32);
      acc = __builtin_amdgcn_mfma_f32_16x16x32_bf16(afrag[kk], b, acc, 0, 0, 0);
    }
    float bias = B[col];
    int orow = row0 + quad * 4;
#pragma unroll
    for (int r = 0; r < 4; r++)
      if (orow + r < M) Y[(size_t)(orow + r) * N + col] = (bf16_t)(acc[r] + bias);
  }
}

// ---------------------------------------------------------------------------
// Multi-config MFMA GEMM (phase D), runtime column count.
// ---------------------------------------------------------------------------
template <int NCFG>
struct GArgs {
  const bf16_t* X[NCFG];
  const bf16_t* Wt[NCFG];
  const float* Bv[NCFG];
  bf16_t* Y[NCFG];
  int M[NCFG];
  int Ncol[NCFG];
  int blk0[NCFG];
};

template <int NCFG>
__global__ __launch_bounds__(256) void gemm_multi(GArgs<NCFG> a) {
  int c = 0;
#pragma unroll
  for (int i = 1; i < NCFG; i++) if ((int)blockIdx.x >= a.blk0[i]) c = i;
  const bf16_t* X = a.X[c];
  const bf16_t* Wt = a.Wt[c];
  const float* B = a.Bv[c];
  bf16_t* Y = a.Y[c];
  int M = a.M[c];
  int N = a.Ncol[c];

  int wv = threadIdx.x >> 6, lane = threadIdx.x & 63;
  int m16 = lane & 15, quad = lane >> 4;
  int row0 = (blockIdx.x - a.blk0[c]) * 64 + wv * 16;
  int arow = row0 + m16;
  const bf16_t* xp = X + (size_t)arow * DIM + quad * 8;

  bf16x8 afrag[4];
#pragma unroll
  for (int kk = 0; kk < 4; kk++) {
    bf16x8 av = {};
    if (arow < M) av = *reinterpret_cast<const bf16x8*>(xp + kk * 32);
    afrag[kk] = av;
  }

  int ncols = N >> 4;
  for (int nt = 0; nt < ncols; nt++) {
    int col = nt * 16 + m16;
    const bf16_t* bptr = Wt + (size_t)col * DIM + quad * 8;
    floatx4 acc = {0.f, 0.f, 0.f, 0.f};
#pragma unroll
    for (int kk = 0; kk < 4; kk++) {
      bf16x8 b = *reinterpret_cast<const bf16x8*>(bptr + kk * 32);
      acc = __builtin_amdgcn_mfma_f32_16x16x32_bf16(afrag[kk], b, acc, 0, 0, 0);
    }
    float bias = B[col];
    int orow = row0 + quad * 4;
#pragma unroll
    for (int r = 0; r < 4; r++)
      if (orow + r < M) Y[(size_t)(orow + r) * N + col] = (bf16_t)(acc[r] + bias);
  }
}

// ---------------------------------------------------------------------------
// Fused phase-C gather, GROUP-PER-DST layout (NC=128, 8 ch per lane,
// 16-lane groups; head = gl>>2 -> logit reduce = 2 shfls, no dst select).
// Packed 4B meta: one shfl per edge, decode locally.
// NOTE: do NOT use readfirstlane+scalar branch per edge (R10: 73 us vs 55).
// ---------------------------------------------------------------------------
#define SGB 3125                    // 50000 dsts / (4 waves * 4 dsts)
__global__ __launch_bounds__(256) void gatC(
    const int* __restrict__ rp, const unsigned* __restrict__ meta,
    const float* __restrict__ WeS, const float* __restrict__ attS,
    const float* __restrict__ boS,
    const bf16_t* __restrict__ xlS, const bf16_t* __restrict__ xrS,
    bf16_t* __restrict__ outS,
    const float* __restrict__ WeG, const float* __restrict__ attG,
    const float* __restrict__ boG,
    const bf16_t* __restrict__ xlG, const bf16_t* __restrict__ xrG,
    const bf16_t* __restrict__ slG, bf16_t* __restrict__ outG) {
  __shared__ unsigned smeta[256];
  __shared__ float lacc[16][128];
  __shared__ float lden[16][4];
  int lane = threadIdx.x & 63, wv = threadIdx.x >> 6;
  int gl = lane & 15, grp = lane >> 4;

  if (blockIdx.x < SGB) {
    // ---------------- sg: 4 dsts per wave, one per 16-lane group ----------
    int wid = blockIdx.x * 4 + wv;
    int d0 = wid * 4;
    int q = lane < 5 ? lane : 0;
    int rv = rp[d0 + q];
    int beg = __shfl(rv, grp), end = __shfl(rv, grp + 1);
    int dst = d0 + grp;

    float wev[8], atv[8], xrv[8], acc[8];
    *reinterpret_cast<float4*>(wev) = *reinterpret_cast<const float4*>(WeS + gl * 8);
    *reinterpret_cast<float4*>(wev + 4) = *reinterpret_cast<const float4*>(WeS + gl * 8 + 4);
    *reinterpret_cast<float4*>(atv) = *reinterpret_cast<const float4*>(attS + gl * 8);
    *reinterpret_cast<float4*>(atv + 4) = *reinterpret_cast<const float4*>(attS + gl * 8 + 4);
    bf16x8 xrb = *reinterpret_cast<const bf16x8*>(xrS + (size_t)dst * 128 + gl * 8);
#pragma unroll
    for (int v = 0; v < 8; v++) { xrv[v] = (float)xrb[v]; acc[v] = 0.f; }
    float den = 0.f;

    for (int i0 = beg; i0 < end; i0 += 16) {
      int cnt = min(16, end - i0);
      int mv_l = 0;
      if (gl < cnt) mv_l = (int)meta[i0 + gl];
      int base = lane & 48;
      // 1-deep prefetch of next edge's row
      int mvk = __shfl(mv_l, base);
      bf16x8 xlb = *reinterpret_cast<const bf16x8*>(
          xlS + (size_t)(mvk & 0xFFFF) * 128 + gl * 8);
      for (int k = 0; k < cnt; k++) {
        bf16x8 cur = xlb;
        float eac = __uint_as_float((unsigned)mvk & 0xFFFF0000u);
        if (k + 1 < cnt) {
          mvk = __shfl(mv_l, base + k + 1);
          xlb = *reinterpret_cast<const bf16x8*>(
              xlS + (size_t)(mvk & 0xFFFF) * 128 + gl * 8);
        }
        float p = 0.f, xf[8];
#pragma unroll
        for (int v = 0; v < 8; v++) {
          xf[v] = (float)cur[v];
          float z = fmaf(eac, wev[v], xrv[v]) + xf[v];
          z = z > 0.f ? z : 0.2f * z;            // leaky_relu(., 0.2)
          p = fmaf(z, atv[v], p);
        }
        p += __shfl_xor(p, 1);
        p += __shfl_xor(p, 2);                   // head-wide logit (4 lanes)
        float ex = __expf(p);
        den += ex;
#pragma unroll
        for (int v = 0; v < 8; v++) acc[v] = fmaf(ex, xf[v], acc[v]);
      }
    }
    float inv = den > 0.f ? 1.f / den : 0.f;
    bf16x8 o;
#pragma unroll
    for (int v = 0; v < 8; v++) {
      float val = acc[v] * inv + boS[gl * 8 + v];
      o[v] = (bf16_t)(val > 0.f ? val : 0.f);
    }
    *reinterpret_cast<bf16x8*>(outS + (size_t)dst * 128 + gl * 8) = o;
  } else {
    // ---------------- gs: one block per dst, 16 groups over LDS stage -----
    int d = (int)blockIdx.x - SGB;
    const int* rpg = rp + NG;
    int G = wv * 4 + grp;
    int tid = threadIdx.x;

    float wev[8], atv[8], xrv[8], acc[8];
    *reinterpret_cast<float4*>(wev) = *reinterpret_cast<const float4*>(WeG + gl * 8);
    *reinterpret_cast<float4*>(wev + 4) = *reinterpret_cast<const float4*>(WeG + gl * 8 + 4);
    *reinterpret_cast<float4*>(atv) = *reinterpret_cast<const float4*>(attG + gl * 8);
    *reinterpret_cast<float4*>(atv + 4) = *reinterpret_cast<const float4*>(attG + gl * 8 + 4);
    bf16x8 xrb = *reinterpret_cast<const bf16x8*>(xrG + (size_t)d * 128 + gl * 8);
#pragma unroll
    for (int v = 0; v < 8; v++) { xrv[v] = (float)xrb[v]; acc[v] = 0.f; }
    float den = 0.f;

    int beg = rpg[d], end = rpg[d + 1];
    for (int base = beg; base < end; base += 256) {
      int cntb = min(256, end - base);
      __syncthreads();
      if (tid < cntb) smeta[tid] = meta[base + tid];
      __syncthreads();
      int e = G;
      unsigned mv; bf16x8 xlb;
      if (e < cntb) {
        mv = smeta[e];
        xlb = *reinterpret_cast<const bf16x8*>(xlG + (size_t)(mv & 0xFFFF) * 128 + gl * 8);
      }
      while (e < cntb) {
        bf16x8 cur = xlb;
        float eac = __uint_as_float(mv & 0xFFFF0000u);
        int en = e + 16;
        if (en < cntb) {
          mv = smeta[en];
          xlb = *reinterpret_cast<const bf16x8*>(xlG + (size_t)(mv & 0xFFFF) * 128 + gl * 8);
        }
        float p = 0.f, xf[8];
#pragma unroll
        for (int v = 0; v < 8; v++) {
          xf[v] = (float)cur[v];
          float z = fmaf(eac, wev[v], xrv[v]) + xf[v];
          z = z > 0.f ? z : 0.2f * z;
          p = fmaf(z, atv[v], p);
        }
        p += __shfl_xor(p, 1);
        p += __shfl_xor(p, 2);
        float ex = __expf(p);
        den += ex;
#pragma unroll
        for (int v = 0; v < 8; v++) acc[v] = fmaf(ex, xf[v], acc[v]);
        e = en;
      }
    }
#pragma unroll
    for (int v = 0; v < 8; v++) lacc[G][gl * 8 + v] = acc[v];
    if ((gl & 3) == 0) lden[G][gl >> 2] = den;
    __syncthreads();
    if (wv != 0) return;
    int ch = lane * 2;
    int h = lane >> 4;
    float a0 = 0.f, a1 = 0.f, dh = 0.f;
#pragma unroll
    for (int g2 = 0; g2 < 16; g2++) {
      a0 += lacc[g2][ch];
      a1 += lacc[g2][ch + 1];
      dh += lden[g2][h];
    }
    float inv = dh > 0.f ? 1.f / dh : 0.f;
    float v0 = a0 * inv + boG[ch] + (float)slG[(size_t)d * 32 + (ch & 31)];
    float v1 = a1 * inv + boG[ch + 1] + (float)slG[(size_t)d * 32 + ((ch + 1) & 31)];
    bf16x2 o;
    o[0] = (bf16_t)(v0 > 0.f ? v0 : 0.f);
    o[1] = (bf16_t)(v1 > 0.f ? v1 : 0.f);
    *reinterpret_cast<bf16x2*>(outG + (size_t)d * 128 + ch) = o;
  }
}

// ---------------------------------------------------------------------------
// Phase-E gather: one block per dst; 16 groups of 16 lanes, 16 ch/lane
// (NC=256); LDS-staged packed meta + LDS combine; head-mean -> fp32 out.
// ---------------------------------------------------------------------------
__global__ __launch_bounds__(256) void gatE(
    const int* __restrict__ rp, const unsigned* __restrict__ meta,
    const float* __restrict__ We, const float* __restrict__ att,
    const bf16_t* __restrict__ xl, const bf16_t* __restrict__ xr,
    const float* __restrict__ bo, const bf16_t* __restrict__ sl,
    float* __restrict__ out) {
  __shared__ unsigned smeta[256];
  __shared__ float lacc[16][256];
  __shared__ float lden[16][4];
  int lane = threadIdx.x & 63, wv = threadIdx.x >> 6;
  int gl = lane & 15, grp = lane >> 4;
  int G = wv * 4 + grp;
  int tid = threadIdx.x;
  int d = blockIdx.x;

  float wev[16], atv[16], xrv[16], acc[16];
#pragma unroll
  for (int b = 0; b < 4; b++) {
    *reinterpret_cast<float4*>(wev + b * 4) =
        *reinterpret_cast<const float4*>(We + gl * 16 + b * 4);
    *reinterpret_cast<float4*>(atv + b * 4) =
        *reinterpret_cast<const float4*>(att + gl * 16 + b * 4);
  }
  {
    bf16x8 r0 = *reinterpret_cast<const bf16x8*>(xr + (size_t)d * 256 + gl * 16);
    bf16x8 r1 = *reinterpret_cast<const bf16x8*>(xr + (size_t)d * 256 + gl * 16 + 8);
#pragma unroll
    for (int v = 0; v < 8; v++) { xrv[v] = (float)r0[v]; xrv[v + 8] = (float)r1[v]; }
  }
#pragma unroll
  for (int v = 0; v < 16; v++) acc[v] = 0.f;
  float den = 0.f;

  int beg = rp[d], end = rp[d + 1];
  for (int base = beg; base < end; base += 256) {
    int cntb = min(256, end - base);
    __syncthreads();
    if (tid < cntb) smeta[tid] = meta[base + tid];
    __syncthreads();
    int e = G;
    unsigned mv; bf16x8 x0, x1;
    if (e < cntb) {
      mv = smeta[e];
      x0 = *reinterpret_cast<const bf16x8*>(xl + (size_t)(mv & 0xFFFF) * 256 + gl * 16);
      x1 = *reinterpret_cast<const bf16x8*>(xl + (size_t)(mv & 0xFFFF) * 256 + gl * 16 + 8);
    }
    while (e < cntb) {
      bf16x8 c0 = x0, c1 = x1;
      float eac = __uint_as_float(mv & 0xFFFF0000u);
      int en = e + 16;
      if (en < cntb) {
        mv = smeta[en];
        x0 = *reinterpret_cast<const bf16x8*>(xl + (size_t)(mv & 0xFFFF) * 256 + gl * 16);
        x1 = *reinterpret_cast<const bf16x8*>(xl + (size_t)(mv & 0xFFFF) * 256 + gl * 16 + 8);
      }
      float p = 0.f, xf[16];
#pragma unroll
      for (int v = 0; v < 8; v++) { xf[v] = (float)c0[v]; xf[v + 8] = (float)c1[v]; }
#pragma unroll
      for (int v = 0; v < 16; v++) {
        float z = fmaf(eac, wev[v], xrv[v]) + xf[v];
        z = z > 0.f ? z : 0.2f * z;              // leaky_relu(., 0.2)
        p = fmaf(z, atv[v], p);
      }
      p += __shfl_xor(p, 1);
      p += __shfl_xor(p, 2);                     // head-wide logit (4 lanes)
      float ex = __expf(p);
      den += ex;
#pragma unroll
      for (int v = 0; v < 16; v++) acc[v] = fmaf(ex, xf[v], acc[v]);
      e = en;
    }
  }
#pragma unroll
  for (int v = 0; v < 16; v++) lacc[G][gl * 16 + v] = acc[v];
  if ((gl & 3) == 0) lden[G][gl >> 2] = den;
  __syncthreads();
  if (wv != 0) return;
  int ch = lane * 4;
  int h = lane >> 4;
  float a[4] = {0.f, 0.f, 0.f, 0.f};
  float dh = 0.f;
#pragma unroll
  for (int g2 = 0; g2 < 16; g2++) {
#pragma unroll
    for (int v = 0; v < 4; v++) a[v] += lacc[g2][ch + v];
    dh += lden[g2][h];
  }
  float inv = dh > 0.f ? 1.f / dh : 0.f;
#pragma unroll
  for (int v = 0; v < 4; v++) {
    float s_ = a[v] * inv;
    s_ += __shfl_xor(s_, 16);
    s_ += __shfl_xor(s_, 32);                    // sum over the 4 heads
    if (lane < 16) {
      int c = (lane & 15) * 4 + v;
      float val = 0.25f * s_ + bo[c] + (float)sl[(size_t)d * 64 + c];
      out[(size_t)d * 64 + c] = val > 0.f ? val : 0.f;
    }
  }
}

// ---------------------------------------------------------------------------

static inline int nblk(long long threads) { return (int)((threads + 255) / 256); }
static inline int nrow(int M, int R) { return (M + R - 1) / R; }

extern "C" void kernel_launch(void* const* d_in, const int* in_sizes, int n_in,
                              void* d_out, int out_size, void* d_ws, size_t ws_size,
                              hipStream_t stream) {
  const float* x_mrna = (const float*)d_in[0];
  const float* x_gene = (const float*)d_in[1];
  const int* sg_src = (const int*)d_in[2];
  const int* sg_dst = (const int*)d_in[3];
  const int* gs_src = (const int*)d_in[4];
  const int* gs_dst = (const int*)d_in[5];
  const float* ea_sg = (const float*)d_in[6];
  const float* ea_gs = (const float*)d_in[7];
  const float* Wl1_sg = (const float*)d_in[8];
  const float* bl1_sg = (const float*)d_in[9];
  const float* Wr1_sg = (const float*)d_in[10];
  const float* br1_sg = (const float*)d_in[11];
  const float* We1_sg = (const float*)d_in[12];
  const float* att1_sg = (const float*)d_in[13];
  const float* bo1_sg = (const float*)d_in[14];
  const float* Wl1_gs = (const float*)d_in[15];
  const float* bl1_gs = (const float*)d_in[16];
  const float* Wr1_gs = (const float*)d_in[17];
  const float* br1_gs = (const float*)d_in[18];
  const float* We1_gs = (const float*)d_in[19];
  const float* att1_gs = (const float*)d_in[20];
  const float* bo1_gs = (const float*)d_in[21];
  const float* Wl3_gs = (const float*)d_in[22];
  const float* bl3_gs = (const float*)d_in[23];
  const float* Wr3_gs = (const float*)d_in[24];
  const float* br3_gs = (const float*)d_in[25];
  const float* We3_gs = (const float*)d_in[26];
  const float* att3_gs = (const float*)d_in[27];
  const float* bo3_gs = (const float*)d_in[28];
  const float* Wsl1 = (const float*)d_in[29];
  const float* bsl1 = (const float*)d_in[30];
  const float* Wsl3 = (const float*)d_in[31];
  const float* bsl3 = (const float*)d_in[32];

  // ---- workspace arena (fp32 element offsets), bf16 throughout ----
  float* ws = (float*)d_ws;
  bf16_t* xl1_gs = (bf16_t*)(ws + 0);        // bf16[50000*128] dead after C
  bf16_t* xl1_sg = (bf16_t*)(ws + 3200000);  // bf16[4000*128]  dead after C
  bf16_t* xr1_sg = (bf16_t*)(ws + 3456000);  // bf16[50000*128] dead after C
  bf16_t* xr1_gs = (bf16_t*)(ws + 6656000);  // bf16[4000*128]  dead after C
  bf16_t* xl3    = (bf16_t*)(ws + 0);        // bf16[50000*256] aliases [0,6.4M)
  bf16_t* xr3    = (bf16_t*)(ws + 6400000);  // bf16[4000*256]  aliases tail
  bf16_t* xb_mrna = (bf16_t*)(ws + 6912000); // bf16[4000*128]
  bf16_t* xb_gene = (bf16_t*)(ws + 7168000); // bf16[50000*128]
  bf16_t* x1_gene = (bf16_t*)(ws + 10368000);// bf16[50000*128]
  bf16_t* x1_mrna = (bf16_t*)(ws + 13568000);// bf16[4000*128]
  bf16_t* sl1    = (bf16_t*)(ws + 13824000); // bf16[4000*32]
  bf16_t* sl3    = (bf16_t*)(ws + 13856000); // bf16[4000*64]
  int*   ib      = (int*)(ws + 13920000);
  int* cnt  = ib + 0;                   // [54000] zeroed by memset
  int* rpc  = ib + 54000;               // [54001]
  unsigned short* rank_sg = (unsigned short*)(ib + 108002);  // [250000]
  unsigned short* rank_gs = (unsigned short*)(ib + 233002);  // [250000]
  unsigned* meta = (unsigned*)(ib + 358002);  // [500000] packed src|ea-bf16
  bf16_t* wtb = (bf16_t*)(ib + 858002); // [143360] bf16 transposed weights
  // end: ib + 929682 ints -> total ~59.4 MB

  bf16_t* wt_l1sg = wtb + 0;
  bf16_t* wt_r1sg = wtb + 16384;
  bf16_t* wt_l1gs = wtb + 32768;
  bf16_t* wt_r1gs = wtb + 49152;
  bf16_t* wt_l3   = wtb + 65536;   // [256*128]
  bf16_t* wt_r3   = wtb + 98304;   // [256*128]
  bf16_t* wt_sl1  = wtb + 131072;  // [32*128]
  bf16_t* wt_sl3  = wtb + 135168;  // [64*128]

  // zero histogram counters (ws is poisoned 0xAA before every timed call)
  hipMemsetAsync(cnt, 0, 54000 * sizeof(int), stream);

  // ---- phase A1: fused histogram(+rank) + weight/x prep ----
  {
    HPArgs hp;
    hp.sgd = sg_dst; hp.gsd = gs_dst;
    hp.cnt = cnt; hp.rank_sg = rank_sg; hp.rank_gs = rank_gs;
    const float* Wsrc[8] = {Wl1_sg, Wr1_sg, Wl1_gs, Wr1_gs, Wl3_gs, Wr3_gs, Wsl1, Wsl3};
    bf16_t* Wdst[8] = {wt_l1sg, wt_r1sg, wt_l1gs, wt_r1gs, wt_l3, wt_r3, wt_sl1, wt_sl3};
    int Nn[8] = {128, 128, 128, 128, 256, 256, 32, 64};
    int e0[8] = {0, 16384, 32768, 49152, 65536, 98304, 131072, 135168};
    for (int i = 0; i < 8; i++) { hp.W[i] = Wsrc[i]; hp.Wt[i] = Wdst[i]; hp.N[i] = Nn[i]; hp.e0[i] = e0[i]; }
    hp.xm = x_mrna; hp.xbm = xb_mrna;
    hp.xg = x_gene; hp.xbg = xb_gene;
    histprep<<<HIST_B + 7310, 256, 0, stream>>>(hp);   // 8287 blocks
  }

  // ---- phase A2: single-kernel parallel scan ----
  int nchunks = (NDST_TOT + 1023) / 1024;            // 53
  scan_f<<<nchunks, 1024, 0, stream>>>(cnt, rpc, NDST_TOT);

  // ---- phase B: interleaved atomic-free scatter + 5 layer-1 GEMMs ----
  {
    SGArgs sa;
    sa.sgd = sg_dst; sa.gsd = gs_dst; sa.sgs = sg_src; sa.gss = gs_src;
    sa.easg = ea_sg; sa.eags = ea_gs;
    sa.rp = rpc; sa.rank_sg = rank_sg; sa.rank_gs = rank_gs; sa.meta = meta;
    const bf16_t* Xs[5] = {xb_mrna, xb_gene, xb_gene, xb_mrna, xb_mrna};
    const bf16_t* Ws[5] = {wt_l1sg, wt_r1sg, wt_l1gs, wt_r1gs, wt_sl1};
    const float* Bs[5] = {bl1_sg, br1_sg, bl1_gs, br1_gs, bsl1};
    bf16_t* Ys[5] = {xl1_sg, xr1_sg, xl1_gs, xr1_gs, sl1};
    int Ms[5] = {NS, NG, NG, NS, NS};
    int Ns[5] = {128, 128, 128, 128, 32};
    int b0 = 0;
    for (int i = 0; i < 5; i++) {
      sa.X[i] = Xs[i]; sa.Wt[i] = Ws[i]; sa.Bv[i] = Bs[i]; sa.Y[i] = Ys[i];
      sa.M[i] = Ms[i]; sa.Ncol[i] = Ns[i]; sa.blk0[i] = b0;
      b0 += nrow(Ms[i], 64);
    }
    // first 2*HIST_B blocks alternate scatter/gemm; rest are gemm
    scatgemm<<<HIST_B + b0, 256, 0, stream>>>(sa);   // 977 + 1753 = 2730
  }

  // ---- phase C: fused layer-1 gathers ----
  gatC<<<SGB + NS, 256, 0, stream>>>(
      rpc, meta,
      We1_sg, att1_sg, bo1_sg, xl1_sg, xr1_sg, x1_gene,
      We1_gs, att1_gs, bo1_gs, xl1_gs, xr1_gs, sl1, x1_mrna);

  // ---- phase D: 3 fused layer-3 GEMMs (incl. sl3) ----
  {
    GArgs<3> ga;
    const bf16_t* Xs[3] = {x1_gene, x1_mrna, x1_mrna};
    const bf16_t* Ws[3] = {wt_l3, wt_r3, wt_sl3};
    const float* Bs[3] = {bl3_gs, br3_gs, bsl3};
    bf16_t* Ys[3] = {xl3, xr3, sl3};
    int Ms[3] = {NG, NS, NS};
    int Ns[3] = {256, 256, 64};
    int b0 = 0;
    for (int i = 0; i < 3; i++) {
      ga.X[i] = Xs[i]; ga.Wt[i] = Ws[i]; ga.Bv[i] = Bs[i]; ga.Y[i] = Ys[i];
      ga.M[i] = Ms[i]; ga.Ncol[i] = Ns[i]; ga.blk0[i] = b0;
      b0 += nrow(Ms[i], 64);
    }
    gemm_multi<3><<<b0, 256, 0, stream>>>(ga);   // 908 blocks
  }

  // ---- phase E: layer-3 gather (head-mean/self-loop/relu) -> d_out ----
  gatE<<<NS, 256, 0, stream>>>(rpc + NG, meta, We3_gs, att3_gs,
                               xl3, xr3, bo3_gs, sl3, (float*)d_out);
}

// Round 15
// 304.981 us; speedup vs baseline: 1.0323x; 1.0323x over previous
//
#include <hip/hip_runtime.h>
#include <cstdint>
#include <cstddef>

// Problem constants (match reference)
#define NS 4000
#define NG 50000
#define NE 250000
#define DIM 128
#define NDST_TOT (NG + NS)          // 54000 combined CSR rows (sg then gs)

typedef __bf16 bf16_t;
typedef bf16_t bf16x8 __attribute__((ext_vector_type(8)));
typedef bf16_t bf16x4 __attribute__((ext_vector_type(4)));
typedef bf16_t bf16x2 __attribute__((ext_vector_type(2)));
typedef float floatx4 __attribute__((ext_vector_type(4)));

// packed edge meta: low 16 = src id (< 65536), high 16 = bf16 bits of ea
__device__ __forceinline__ unsigned pack_meta(int src, float ea) {
  union { bf16_t b; unsigned short u; } cv;
  cv.b = (bf16_t)ea;
  return (unsigned)src | ((unsigned)cv.u << 16);
}
// decode: src = mv & 0xFFFF; ea = __uint_as_float(mv & 0xFFFF0000u)

// ---------------------------------------------------------------------------
// Fused histogram + prep. Blocks [0, HIST_B): per-dst degree counts; the
// atomicAdd return IS the edge's rank within its dst (ushort) -> scatter
// needs no atomics. Blocks [HIST_B, ...): 8 weight transposes + bf16 x casts.
// ---------------------------------------------------------------------------
#define HIST_B 977                  // ceil(NE/256)
#define WT_TOT 143360               // 4*16384 + 2*32768 + 4096 + 8192
struct HPArgs {
  const int* sgd; const int* gsd;
  int* cnt; unsigned short* rank_sg; unsigned short* rank_gs;
  const float* W[8]; bf16_t* Wt[8]; int N[8]; int e0[8];
  const float* xm; bf16_t* xbm;
  const float* xg; bf16_t* xbg;
};

__global__ __launch_bounds__(256) void histprep(HPArgs a) {
  if (blockIdx.x < HIST_B) {
    int e = blockIdx.x * 256 + threadIdx.x;
    if (e < NE) {
      a.rank_sg[e] = (unsigned short)atomicAdd(a.cnt + a.sgd[e], 1);
      a.rank_gs[e] = (unsigned short)atomicAdd(a.cnt + NG + a.gsd[e], 1);
    }
  } else {
    int u = (blockIdx.x - HIST_B) * 256 + threadIdx.x;
    if (u < WT_TOT) {
      int c = 0;
#pragma unroll
      for (int i = 1; i < 8; i++) if (u >= a.e0[i]) c = i;
      int idx = u - a.e0[c];
      int N = a.N[c];
      int k = idx / N, n = idx - k * N;
      a.Wt[c][n * 128 + k] = (bf16_t)a.W[c][idx];
    } else if (u < WT_TOT + 128000) {
      int j = (u - WT_TOT) * 4;
      float4 v = *reinterpret_cast<const float4*>(a.xm + j);
      bf16x4 b;
      b[0] = (bf16_t)v.x; b[1] = (bf16_t)v.y; b[2] = (bf16_t)v.z; b[3] = (bf16_t)v.w;
      *reinterpret_cast<bf16x4*>(a.xbm + j) = b;
    } else {
      int j = (u - WT_TOT - 128000) * 4;
      float4 v = *reinterpret_cast<const float4*>(a.xg + j);
      bf16x4 b;
      b[0] = (bf16_t)v.x; b[1] = (bf16_t)v.y; b[2] = (bf16_t)v.z; b[3] = (bf16_t)v.w;
      *reinterpret_cast<bf16x4*>(a.xbg + j) = b;
    }
  }
}

// ---------------------------------------------------------------------------
// Single-kernel exclusive scan over n=54000 (53 blocks of 1024). Block b
// redundantly reduces cnt[0, b*1024) — block-parallel + coalesced (L2-hot)
// — then scans its own chunk. NOTE: do NOT serialize onto one block
// (R8: 103 us from per-thread serial reads); redundant-parallel is fine.
// ---------------------------------------------------------------------------
__global__ __launch_bounds__(1024) void scan_f(const int* __restrict__ cnt,
                                               int* __restrict__ rp, int n) {
  __shared__ int wsum[16];
  __shared__ int base_s;
  int t = threadIdx.x;
  int lane = t & 63, w = t >> 6;
  int lim = blockIdx.x * 1024;
  int s = 0;
  for (int i = t; i < lim; i += 1024) s += cnt[i];
#pragma unroll
  for (int off = 32; off > 0; off >>= 1) s += __shfl_down(s, off);
  if (lane == 0) wsum[w] = s;
  __syncthreads();
  if (t == 0) {
    int tot = 0;
#pragma unroll
    for (int i = 0; i < 16; i++) tot += wsum[i];
    base_s = tot;
  }
  __syncthreads();
  int base = base_s;
  int i = blockIdx.x * 1024 + t;
  int v = (i < n) ? cnt[i] : 0;
  int x = v;
#pragma unroll
  for (int off = 1; off < 64; off <<= 1) {
    int y = __shfl_up(x, off);
    if (lane >= off) x += y;
  }
  if (lane == 63) wsum[w] = x;
  __syncthreads();
  if (w == 0 && lane < 16) {
    int ss = wsum[lane];
#pragma unroll
    for (int off = 1; off < 16; off <<= 1) {
      int y = __shfl_up(ss, off);
      if (lane >= off) ss += y;
    }
    wsum[lane] = ss;
  }
  __syncthreads();
  int incl = x + (w ? wsum[w - 1] : 0);
  if (i < n) rp[i] = base + incl - v;
  if (i == 0) rp[n] = 2 * NE;                // static total sentinel
}

// ---------------------------------------------------------------------------
// Fused scatter + layer-1 GEMMs, RANGE split (R13 structure — measured best).
// NOTE: do NOT parity-interleave with a dual-edge scatter (R14: 53 us vs 47;
// halving scatter blocks lengthens the scatter long-pole). One edge/thread,
// 1954 scatter blocks, atomic-free via precomputed rank.
// ---------------------------------------------------------------------------
#define SCAT_B 1954                 // ceil(2*NE/256)
struct SGArgs {
  const int* sgd; const int* gsd; const int* sgs; const int* gss;
  const float* easg; const float* eags;
  const int* rp; const unsigned short* rank_sg; const unsigned short* rank_gs;
  unsigned* meta;
  const bf16_t* X[5];
  const bf16_t* Wt[5];
  const float* Bv[5];
  bf16_t* Y[5];
  int M[5];
  int Ncol[5];
  int blk0[5];
};

__global__ __launch_bounds__(256) void scatgemm(SGArgs a) {
  if (blockIdx.x < SCAT_B) {
    int t = blockIdx.x * 256 + threadIdx.x;
    if (t < NE) {
      int d = a.sgd[t];
      a.meta[a.rp[d] + a.rank_sg[t]] = pack_meta(a.sgs[t], a.easg[t]);
    } else if (t < 2 * NE) {
      int e = t - NE;
      int d = a.gsd[e];
      a.meta[a.rp[NG + d] + a.rank_gs[e]] = pack_meta(a.gss[e], a.eags[e]);
    }
    return;
  }
  int bid = blockIdx.x - SCAT_B;
  int c = 0;
#pragma unroll
  for (int i = 1; i < 5; i++) if (bid >= a.blk0[i]) c = i;
  const bf16_t* X = a.X[c];
  const bf16_t* Wt = a.Wt[c];
  const float* B = a.Bv[c];
  bf16_t* Y = a.Y[c];
  int M = a.M[c];
  int N = a.Ncol[c];

  int wv = threadIdx.x >> 6, lane = threadIdx.x & 63;
  int m16 = lane & 15, quad = lane >> 4;
  int row0 = (bid - a.blk0[c]) * 64 + wv * 16;
  int arow = row0 + m16;
  const bf16_t* xp = X + (size_t)arow * DIM + quad * 8;

  bf16x8 afrag[4];
#pragma unroll
  for (int kk = 0; kk < 4; kk++) {
    bf16x8 av = {};
    if (arow < M) av = *reinterpret_cast<const bf16x8*>(xp + kk * 32);
    afrag[kk] = av;
  }

  int ncols = N >> 4;
  for (int nt = 0; nt < ncols; nt++) {
    int col = nt * 16 + m16;
    const bf16_t* bptr = Wt + (size_t)col * DIM + quad * 8;
    floatx4 acc = {0.f, 0.f, 0.f, 0.f};
#pragma unroll
    for (int kk = 0; kk < 4; kk++) {
      bf16x8 b = *reinterpret_cast<const bf16x8*>(bptr + kk * 32);
      acc = __builtin_amdgcn_mfma_f32_16x16x32_bf16(afrag[kk], b, acc, 0, 0, 0);
    }
    float bias = B[col];
    int orow = row0 + quad * 4;
#pragma unroll
    for (int r = 0; r < 4; r++)
      if (orow + r < M) Y[(size_t)(orow + r) * N + col] = (bf16_t)(acc[r] + bias);
  }
}

// ---------------------------------------------------------------------------
// Multi-config MFMA GEMM (phase D), runtime column count.
// ---------------------------------------------------------------------------
template <int NCFG>
struct GArgs {
  const bf16_t* X[NCFG];
  const bf16_t* Wt[NCFG];
  const float* Bv[NCFG];
  bf16_t* Y[NCFG];
  int M[NCFG];
  int Ncol[NCFG];
  int blk0[NCFG];
};

template <int NCFG>
__global__ __launch_bounds__(256) void gemm_multi(GArgs<NCFG> a) {
  int c = 0;
#pragma unroll
  for (int i = 1; i < NCFG; i++) if ((int)blockIdx.x >= a.blk0[i]) c = i;
  const bf16_t* X = a.X[c];
  const bf16_t* Wt = a.Wt[c];
  const float* B = a.Bv[c];
  bf16_t* Y = a.Y[c];
  int M = a.M[c];
  int N = a.Ncol[c];

  int wv = threadIdx.x >> 6, lane = threadIdx.x & 63;
  int m16 = lane & 15, quad = lane >> 4;
  int row0 = (blockIdx.x - a.blk0[c]) * 64 + wv * 16;
  int arow = row0 + m16;
  const bf16_t* xp = X + (size_t)arow * DIM + quad * 8;

  bf16x8 afrag[4];
#pragma unroll
  for (int kk = 0; kk < 4; kk++) {
    bf16x8 av = {};
    if (arow < M) av = *reinterpret_cast<const bf16x8*>(xp + kk * 32);
    afrag[kk] = av;
  }

  int ncols = N >> 4;
  for (int nt = 0; nt < ncols; nt++) {
    int col = nt * 16 + m16;
    const bf16_t* bptr = Wt + (size_t)col * DIM + quad * 8;
    floatx4 acc = {0.f, 0.f, 0.f, 0.f};
#pragma unroll
    for (int kk = 0; kk < 4; kk++) {
      bf16x8 b = *reinterpret_cast<const bf16x8*>(bptr + kk * 32);
      acc = __builtin_amdgcn_mfma_f32_16x16x32_bf16(afrag[kk], b, acc, 0, 0, 0);
    }
    float bias = B[col];
    int orow = row0 + quad * 4;
#pragma unroll
    for (int r = 0; r < 4; r++)
      if (orow + r < M) Y[(size_t)(orow + r) * N + col] = (bf16_t)(acc[r] + bias);
  }
}

// ---------------------------------------------------------------------------
// Fused phase-C gather, GROUP-PER-DST layout (NC=128, 8 ch per lane,
// 16-lane groups; head = gl>>2 -> logit reduce = 2 shfls, no dst select).
// Packed 4B meta: one shfl per edge, decode locally.
// NOTE: do NOT use readfirstlane+scalar branch per edge (R10: 73 us vs 55).
// ---------------------------------------------------------------------------
#define SGB 3125                    // 50000 dsts / (4 waves * 4 dsts)
__global__ __launch_bounds__(256) void gatC(
    const int* __restrict__ rp, const unsigned* __restrict__ meta,
    const float* __restrict__ WeS, const float* __restrict__ attS,
    const float* __restrict__ boS,
    const bf16_t* __restrict__ xlS, const bf16_t* __restrict__ xrS,
    bf16_t* __restrict__ outS,
    const float* __restrict__ WeG, const float* __restrict__ attG,
    const float* __restrict__ boG,
    const bf16_t* __restrict__ xlG, const bf16_t* __restrict__ xrG,
    const bf16_t* __restrict__ slG, bf16_t* __restrict__ outG) {
  __shared__ unsigned smeta[256];
  __shared__ float lacc[16][128];
  __shared__ float lden[16][4];
  int lane = threadIdx.x & 63, wv = threadIdx.x >> 6;
  int gl = lane & 15, grp = lane >> 4;

  if (blockIdx.x < SGB) {
    // ---------------- sg: 4 dsts per wave, one per 16-lane group ----------
    int wid = blockIdx.x * 4 + wv;
    int d0 = wid * 4;
    int q = lane < 5 ? lane : 0;
    int rv = rp[d0 + q];
    int beg = __shfl(rv, grp), end = __shfl(rv, grp + 1);
    int dst = d0 + grp;

    float wev[8], atv[8], xrv[8], acc[8];
    *reinterpret_cast<float4*>(wev) = *reinterpret_cast<const float4*>(WeS + gl * 8);
    *reinterpret_cast<float4*>(wev + 4) = *reinterpret_cast<const float4*>(WeS + gl * 8 + 4);
    *reinterpret_cast<float4*>(atv) = *reinterpret_cast<const float4*>(attS + gl * 8);
    *reinterpret_cast<float4*>(atv + 4) = *reinterpret_cast<const float4*>(attS + gl * 8 + 4);
    bf16x8 xrb = *reinterpret_cast<const bf16x8*>(xrS + (size_t)dst * 128 + gl * 8);
#pragma unroll
    for (int v = 0; v < 8; v++) { xrv[v] = (float)xrb[v]; acc[v] = 0.f; }
    float den = 0.f;

    for (int i0 = beg; i0 < end; i0 += 16) {
      int cnt = min(16, end - i0);
      int mv_l = 0;
      if (gl < cnt) mv_l = (int)meta[i0 + gl];
      int base = lane & 48;
      // 1-deep prefetch of next edge's row
      int mvk = __shfl(mv_l, base);
      bf16x8 xlb = *reinterpret_cast<const bf16x8*>(
          xlS + (size_t)(mvk & 0xFFFF) * 128 + gl * 8);
      for (int k = 0; k < cnt; k++) {
        bf16x8 cur = xlb;
        float eac = __uint_as_float((unsigned)mvk & 0xFFFF0000u);
        if (k + 1 < cnt) {
          mvk = __shfl(mv_l, base + k + 1);
          xlb = *reinterpret_cast<const bf16x8*>(
              xlS + (size_t)(mvk & 0xFFFF) * 128 + gl * 8);
        }
        float p = 0.f, xf[8];
#pragma unroll
        for (int v = 0; v < 8; v++) {
          xf[v] = (float)cur[v];
          float z = fmaf(eac, wev[v], xrv[v]) + xf[v];
          z = z > 0.f ? z : 0.2f * z;            // leaky_relu(., 0.2)
          p = fmaf(z, atv[v], p);
        }
        p += __shfl_xor(p, 1);
        p += __shfl_xor(p, 2);                   // head-wide logit (4 lanes)
        float ex = __expf(p);
        den += ex;
#pragma unroll
        for (int v = 0; v < 8; v++) acc[v] = fmaf(ex, xf[v], acc[v]);
      }
    }
    float inv = den > 0.f ? 1.f / den : 0.f;
    bf16x8 o;
#pragma unroll
    for (int v = 0; v < 8; v++) {
      float val = acc[v] * inv + boS[gl * 8 + v];
      o[v] = (bf16_t)(val > 0.f ? val : 0.f);
    }
    *reinterpret_cast<bf16x8*>(outS + (size_t)dst * 128 + gl * 8) = o;
  } else {
    // ---------------- gs: one block per dst, 16 groups over LDS stage -----
    int d = (int)blockIdx.x - SGB;
    const int* rpg = rp + NG;
    int G = wv * 4 + grp;
    int tid = threadIdx.x;

    float wev[8], atv[8], xrv[8], acc[8];
    *reinterpret_cast<float4*>(wev) = *reinterpret_cast<const float4*>(WeG + gl * 8);
    *reinterpret_cast<float4*>(wev + 4) = *reinterpret_cast<const float4*>(WeG + gl * 8 + 4);
    *reinterpret_cast<float4*>(atv) = *reinterpret_cast<const float4*>(attG + gl * 8);
    *reinterpret_cast<float4*>(atv + 4) = *reinterpret_cast<const float4*>(attG + gl * 8 + 4);
    bf16x8 xrb = *reinterpret_cast<const bf16x8*>(xrG + (size_t)d * 128 + gl * 8);
#pragma unroll
    for (int v = 0; v < 8; v++) { xrv[v] = (float)xrb[v]; acc[v] = 0.f; }
    float den = 0.f;

    int beg = rpg[d], end = rpg[d + 1];
    for (int base = beg; base < end; base += 256) {
      int cntb = min(256, end - base);
      __syncthreads();
      if (tid < cntb) smeta[tid] = meta[base + tid];
      __syncthreads();
      int e = G;
      unsigned mv; bf16x8 xlb;
      if (e < cntb) {
        mv = smeta[e];
        xlb = *reinterpret_cast<const bf16x8*>(xlG + (size_t)(mv & 0xFFFF) * 128 + gl * 8);
      }
      while (e < cntb) {
        bf16x8 cur = xlb;
        float eac = __uint_as_float(mv & 0xFFFF0000u);
        int en = e + 16;
        if (en < cntb) {
          mv = smeta[en];
          xlb = *reinterpret_cast<const bf16x8*>(xlG + (size_t)(mv & 0xFFFF) * 128 + gl * 8);
        }
        float p = 0.f, xf[8];
#pragma unroll
        for (int v = 0; v < 8; v++) {
          xf[v] = (float)cur[v];
          float z = fmaf(eac, wev[v], xrv[v]) + xf[v];
          z = z > 0.f ? z : 0.2f * z;
          p = fmaf(z, atv[v], p);
        }
        p += __shfl_xor(p, 1);
        p += __shfl_xor(p, 2);
        float ex = __expf(p);
        den += ex;
#pragma unroll
        for (int v = 0; v < 8; v++) acc[v] = fmaf(ex, xf[v], acc[v]);
        e = en;
      }
    }
#pragma unroll
    for (int v = 0; v < 8; v++) lacc[G][gl * 8 + v] = acc[v];
    if ((gl & 3) == 0) lden[G][gl >> 2] = den;
    __syncthreads();
    if (wv != 0) return;
    int ch = lane * 2;
    int h = lane >> 4;
    float a0 = 0.f, a1 = 0.f, dh = 0.f;
#pragma unroll
    for (int g2 = 0; g2 < 16; g2++) {
      a0 += lacc[g2][ch];
      a1 += lacc[g2][ch + 1];
      dh += lden[g2][h];
    }
    float inv = dh > 0.f ? 1.f / dh : 0.f;
    float v0 = a0 * inv + boG[ch] + (float)slG[(size_t)d * 32 + (ch & 31)];
    float v1 = a1 * inv + boG[ch + 1] + (float)slG[(size_t)d * 32 + ((ch + 1) & 31)];
    bf16x2 o;
    o[0] = (bf16_t)(v0 > 0.f ? v0 : 0.f);
    o[1] = (bf16_t)(v1 > 0.f ? v1 : 0.f);
    *reinterpret_cast<bf16x2*>(outG + (size_t)d * 128 + ch) = o;
  }
}

// ---------------------------------------------------------------------------
// Phase-E gather: one block per dst; 16 groups of 16 lanes, 16 ch/lane
// (NC=256); LDS-staged packed meta + LDS combine; head-mean -> fp32 out.
// ---------------------------------------------------------------------------
__global__ __launch_bounds__(256) void gatE(
    const int* __restrict__ rp, const unsigned* __restrict__ meta,
    const float* __restrict__ We, const float* __restrict__ att,
    const bf16_t* __restrict__ xl, const bf16_t* __restrict__ xr,
    const float* __restrict__ bo, const bf16_t* __restrict__ sl,
    float* __restrict__ out) {
  __shared__ unsigned smeta[256];
  __shared__ float lacc[16][256];
  __shared__ float lden[16][4];
  int lane = threadIdx.x & 63, wv = threadIdx.x >> 6;
  int gl = lane & 15, grp = lane >> 4;
  int G = wv * 4 + grp;
  int tid = threadIdx.x;
  int d = blockIdx.x;

  float wev[16], atv[16], xrv[16], acc[16];
#pragma unroll
  for (int b = 0; b < 4; b++) {
    *reinterpret_cast<float4*>(wev + b * 4) =
        *reinterpret_cast<const float4*>(We + gl * 16 + b * 4);
    *reinterpret_cast<float4*>(atv + b * 4) =
        *reinterpret_cast<const float4*>(att + gl * 16 + b * 4);
  }
  {
    bf16x8 r0 = *reinterpret_cast<const bf16x8*>(xr + (size_t)d * 256 + gl * 16);
    bf16x8 r1 = *reinterpret_cast<const bf16x8*>(xr + (size_t)d * 256 + gl * 16 + 8);
#pragma unroll
    for (int v = 0; v < 8; v++) { xrv[v] = (float)r0[v]; xrv[v + 8] = (float)r1[v]; }
  }
#pragma unroll
  for (int v = 0; v < 16; v++) acc[v] = 0.f;
  float den = 0.f;

  int beg = rp[d], end = rp[d + 1];
  for (int base = beg; base < end; base += 256) {
    int cntb = min(256, end - base);
    __syncthreads();
    if (tid < cntb) smeta[tid] = meta[base + tid];
    __syncthreads();
    int e = G;
    unsigned mv; bf16x8 x0, x1;
    if (e < cntb) {
      mv = smeta[e];
      x0 = *reinterpret_cast<const bf16x8*>(xl + (size_t)(mv & 0xFFFF) * 256 + gl * 16);
      x1 = *reinterpret_cast<const bf16x8*>(xl + (size_t)(mv & 0xFFFF) * 256 + gl * 16 + 8);
    }
    while (e < cntb) {
      bf16x8 c0 = x0, c1 = x1;
      float eac = __uint_as_float(mv & 0xFFFF0000u);
      int en = e + 16;
      if (en < cntb) {
        mv = smeta[en];
        x0 = *reinterpret_cast<const bf16x8*>(xl + (size_t)(mv & 0xFFFF) * 256 + gl * 16);
        x1 = *reinterpret_cast<const bf16x8*>(xl + (size_t)(mv & 0xFFFF) * 256 + gl * 16 + 8);
      }
      float p = 0.f, xf[16];
#pragma unroll
      for (int v = 0; v < 8; v++) { xf[v] = (float)c0[v]; xf[v + 8] = (float)c1[v]; }
#pragma unroll
      for (int v = 0; v < 16; v++) {
        float z = fmaf(eac, wev[v], xrv[v]) + xf[v];
        z = z > 0.f ? z : 0.2f * z;              // leaky_relu(., 0.2)
        p = fmaf(z, atv[v], p);
      }
      p += __shfl_xor(p, 1);
      p += __shfl_xor(p, 2);                     // head-wide logit (4 lanes)
      float ex = __expf(p);
      den += ex;
#pragma unroll
      for (int v = 0; v < 16; v++) acc[v] = fmaf(ex, xf[v], acc[v]);
      e = en;
    }
  }
#pragma unroll
  for (int v = 0; v < 16; v++) lacc[G][gl * 16 + v] = acc[v];
  if ((gl & 3) == 0) lden[G][gl >> 2] = den;
  __syncthreads();
  if (wv != 0) return;
  int ch = lane * 4;
  int h = lane >> 4;
  float a[4] = {0.f, 0.f, 0.f, 0.f};
  float dh = 0.f;
#pragma unroll
  for (int g2 = 0; g2 < 16; g2++) {
#pragma unroll
    for (int v = 0; v < 4; v++) a[v] += lacc[g2][ch + v];
    dh += lden[g2][h];
  }
  float inv = dh > 0.f ? 1.f / dh : 0.f;
#pragma unroll
  for (int v = 0; v < 4; v++) {
    float s_ = a[v] * inv;
    s_ += __shfl_xor(s_, 16);
    s_ += __shfl_xor(s_, 32);                    // sum over the 4 heads
    if (lane < 16) {
      int c = (lane & 15) * 4 + v;
      float val = 0.25f * s_ + bo[c] + (float)sl[(size_t)d * 64 + c];
      out[(size_t)d * 64 + c] = val > 0.f ? val : 0.f;
    }
  }
}

// ---------------------------------------------------------------------------

static inline int nblk(long long threads) { return (int)((threads + 255) / 256); }
static inline int nrow(int M, int R) { return (M + R - 1) / R; }

extern "C" void kernel_launch(void* const* d_in, const int* in_sizes, int n_in,
                              void* d_out, int out_size, void* d_ws, size_t ws_size,
                              hipStream_t stream) {
  const float* x_mrna = (const float*)d_in[0];
  const float* x_gene = (const float*)d_in[1];
  const int* sg_src = (const int*)d_in[2];
  const int* sg_dst = (const int*)d_in[3];
  const int* gs_src = (const int*)d_in[4];
  const int* gs_dst = (const int*)d_in[5];
  const float* ea_sg = (const float*)d_in[6];
  const float* ea_gs = (const float*)d_in[7];
  const float* Wl1_sg = (const float*)d_in[8];
  const float* bl1_sg = (const float*)d_in[9];
  const float* Wr1_sg = (const float*)d_in[10];
  const float* br1_sg = (const float*)d_in[11];
  const float* We1_sg = (const float*)d_in[12];
  const float* att1_sg = (const float*)d_in[13];
  const float* bo1_sg = (const float*)d_in[14];
  const float* Wl1_gs = (const float*)d_in[15];
  const float* bl1_gs = (const float*)d_in[16];
  const float* Wr1_gs = (const float*)d_in[17];
  const float* br1_gs = (const float*)d_in[18];
  const float* We1_gs = (const float*)d_in[19];
  const float* att1_gs = (const float*)d_in[20];
  const float* bo1_gs = (const float*)d_in[21];
  const float* Wl3_gs = (const float*)d_in[22];
  const float* bl3_gs = (const float*)d_in[23];
  const float* Wr3_gs = (const float*)d_in[24];
  const float* br3_gs = (const float*)d_in[25];
  const float* We3_gs = (const float*)d_in[26];
  const float* att3_gs = (const float*)d_in[27];
  const float* bo3_gs = (const float*)d_in[28];
  const float* Wsl1 = (const float*)d_in[29];
  const float* bsl1 = (const float*)d_in[30];
  const float* Wsl3 = (const float*)d_in[31];
  const float* bsl3 = (const float*)d_in[32];

  // ---- workspace arena (fp32 element offsets), bf16 throughout ----
  float* ws = (float*)d_ws;
  bf16_t* xl1_gs = (bf16_t*)(ws + 0);        // bf16[50000*128] dead after C
  bf16_t* xl1_sg = (bf16_t*)(ws + 3200000);  // bf16[4000*128]  dead after C
  bf16_t* xr1_sg = (bf16_t*)(ws + 3456000);  // bf16[50000*128] dead after C
  bf16_t* xr1_gs = (bf16_t*)(ws + 6656000);  // bf16[4000*128]  dead after C
  bf16_t* xl3    = (bf16_t*)(ws + 0);        // bf16[50000*256] aliases [0,6.4M)
  bf16_t* xr3    = (bf16_t*)(ws + 6400000);  // bf16[4000*256]  aliases tail
  bf16_t* xb_mrna = (bf16_t*)(ws + 6912000); // bf16[4000*128]
  bf16_t* xb_gene = (bf16_t*)(ws + 7168000); // bf16[50000*128]
  bf16_t* x1_gene = (bf16_t*)(ws + 10368000);// bf16[50000*128]
  bf16_t* x1_mrna = (bf16_t*)(ws + 13568000);// bf16[4000*128]
  bf16_t* sl1    = (bf16_t*)(ws + 13824000); // bf16[4000*32]
  bf16_t* sl3    = (bf16_t*)(ws + 13856000); // bf16[4000*64]
  int*   ib      = (int*)(ws + 13920000);
  int* cnt  = ib + 0;                   // [54000] zeroed by memset
  int* rpc  = ib + 54000;               // [54001]
  unsigned short* rank_sg = (unsigned short*)(ib + 108002);  // [250000]
  unsigned short* rank_gs = (unsigned short*)(ib + 233002);  // [250000]
  unsigned* meta = (unsigned*)(ib + 358002);  // [500000] packed src|ea-bf16
  bf16_t* wtb = (bf16_t*)(ib + 858002); // [143360] bf16 transposed weights
  // end: ib + 929682 ints -> total ~59.4 MB

  bf16_t* wt_l1sg = wtb + 0;
  bf16_t* wt_r1sg = wtb + 16384;
  bf16_t* wt_l1gs = wtb + 32768;
  bf16_t* wt_r1gs = wtb + 49152;
  bf16_t* wt_l3   = wtb + 65536;   // [256*128]
  bf16_t* wt_r3   = wtb + 98304;   // [256*128]
  bf16_t* wt_sl1  = wtb + 131072;  // [32*128]
  bf16_t* wt_sl3  = wtb + 135168;  // [64*128]

  // zero histogram counters (ws is poisoned 0xAA before every timed call)
  hipMemsetAsync(cnt, 0, 54000 * sizeof(int), stream);

  // ---- phase A1: fused histogram(+rank) + weight/x prep ----
  {
    HPArgs hp;
    hp.sgd = sg_dst; hp.gsd = gs_dst;
    hp.cnt = cnt; hp.rank_sg = rank_sg; hp.rank_gs = rank_gs;
    const float* Wsrc[8] = {Wl1_sg, Wr1_sg, Wl1_gs, Wr1_gs, Wl3_gs, Wr3_gs, Wsl1, Wsl3};
    bf16_t* Wdst[8] = {wt_l1sg, wt_r1sg, wt_l1gs, wt_r1gs, wt_l3, wt_r3, wt_sl1, wt_sl3};
    int Nn[8] = {128, 128, 128, 128, 256, 256, 32, 64};
    int e0[8] = {0, 16384, 32768, 49152, 65536, 98304, 131072, 135168};
    for (int i = 0; i < 8; i++) { hp.W[i] = Wsrc[i]; hp.Wt[i] = Wdst[i]; hp.N[i] = Nn[i]; hp.e0[i] = e0[i]; }
    hp.xm = x_mrna; hp.xbm = xb_mrna;
    hp.xg = x_gene; hp.xbg = xb_gene;
    histprep<<<HIST_B + 7310, 256, 0, stream>>>(hp);   // 8287 blocks
  }

  // ---- phase A2: single-kernel parallel scan ----
  int nchunks = (NDST_TOT + 1023) / 1024;            // 53
  scan_f<<<nchunks, 1024, 0, stream>>>(cnt, rpc, NDST_TOT);

  // ---- phase B: range-split atomic-free scatter + 5 layer-1 GEMMs ----
  {
    SGArgs sa;
    sa.sgd = sg_dst; sa.gsd = gs_dst; sa.sgs = sg_src; sa.gss = gs_src;
    sa.easg = ea_sg; sa.eags = ea_gs;
    sa.rp = rpc; sa.rank_sg = rank_sg; sa.rank_gs = rank_gs; sa.meta = meta;
    const bf16_t* Xs[5] = {xb_mrna, xb_gene, xb_gene, xb_mrna, xb_mrna};
    const bf16_t* Ws[5] = {wt_l1sg, wt_r1sg, wt_l1gs, wt_r1gs, wt_sl1};
    const float* Bs[5] = {bl1_sg, br1_sg, bl1_gs, br1_gs, bsl1};
    bf16_t* Ys[5] = {xl1_sg, xr1_sg, xl1_gs, xr1_gs, sl1};
    int Ms[5] = {NS, NG, NG, NS, NS};
    int Ns[5] = {128, 128, 128, 128, 32};
    int b0 = 0;
    for (int i = 0; i < 5; i++) {
      sa.X[i] = Xs[i]; sa.Wt[i] = Ws[i]; sa.Bv[i] = Bs[i]; sa.Y[i] = Ys[i];
      sa.M[i] = Ms[i]; sa.Ncol[i] = Ns[i]; sa.blk0[i] = b0;
      b0 += nrow(Ms[i], 64);
    }
    scatgemm<<<SCAT_B + b0, 256, 0, stream>>>(sa);   // 1954 + 1753 blocks
  }

  // ---- phase C: fused layer-1 gathers ----
  gatC<<<SGB + NS, 256, 0, stream>>>(
      rpc, meta,
      We1_sg, att1_sg, bo1_sg, xl1_sg, xr1_sg, x1_gene,
      We1_gs, att1_gs, bo1_gs, xl1_gs, xr1_gs, sl1, x1_mrna);

  // ---- phase D: 3 fused layer-3 GEMMs (incl. sl3) ----
  {
    GArgs<3> ga;
    const bf16_t* Xs[3] = {x1_gene, x1_mrna, x1_mrna};
    const bf16_t* Ws[3] = {wt_l3, wt_r3, wt_sl3};
    const float* Bs[3] = {bl3_gs, br3_gs, bsl3};
    bf16_t* Ys[3] = {xl3, xr3, sl3};
    int Ms[3] = {NG, NS, NS};
    int Ns[3] = {256, 256, 64};
    int b0 = 0;
    for (int i = 0; i < 3; i++) {
      ga.X[i] = Xs[i]; ga.Wt[i] = Ws[i]; ga.Bv[i] = Bs[i]; ga.Y[i] = Ys[i];
      ga.M[i] = Ms[i]; ga.Ncol[i] = Ns[i]; ga.blk0[i] = b0;
      b0 += nrow(Ms[i], 64);
    }
    gemm_multi<3><<<b0, 256, 0, stream>>>(ga);   // 908 blocks
  }

  // ---- phase E: layer-3 gather (head-mean/self-loop/relu) -> d_out ----
  gatE<<<NS, 256, 0, stream>>>(rpc + NG, meta, We3_gs, att3_gs,
                               xl3, xr3, bo3_gs, sl3, (float*)d_out);
}